// Round 1
// baseline (610.783 us; speedup 1.0000x reference)
//
#include <hip/hip_runtime.h>
#include <stdint.h>

// Shapes (fixed): B=4, S=2048, D=1024, H=16, DH=64
#define NB 4
#define NS 2048
#define ND 1024
#define NH 16
#define NDH 64

typedef __attribute__((ext_vector_type(8))) short bf16x8;
typedef __attribute__((ext_vector_type(4))) float f32x4;

#define MFMA16(a, b, c) __builtin_amdgcn_mfma_f32_16x16x32_bf16((a), (b), (c), 0, 0, 0)

__device__ __forceinline__ uint16_t f2bf(float f) {
  uint32_t u = __builtin_bit_cast(uint32_t, f);
  return (uint16_t)((u + 0x7FFFu + ((u >> 16) & 1u)) >> 16);
}

__device__ __forceinline__ void gload_lds16(const void* g, void* l) {
  __builtin_amdgcn_global_load_lds(
      (const __attribute__((address_space(1))) uint32_t*)(uintptr_t)g,
      (__attribute__((address_space(3))) uint32_t*)(uintptr_t)l, 16, 0, 0);
}

// ---------------- fp32 -> bf16 convert (x) ----------------
__global__ __launch_bounds__(256) void cvt_bf16_kernel(const float* __restrict__ src,
                                                       uint16_t* __restrict__ dst, int n4) {
  int i = blockIdx.x * 256 + threadIdx.x;
  if (i >= n4) return;
  const float4 f = *(const float4*)(src + (size_t)i * 4);
  union { uint16_t u[4]; uint64_t q; } o;
  o.u[0] = f2bf(f.x); o.u[1] = f2bf(f.y); o.u[2] = f2bf(f.z); o.u[3] = f2bf(f.w);
  *(uint64_t*)(dst + (size_t)i * 4) = o.q;
}

// ---------------- transpose + convert: W[1024][1024] f32 -> Wt[n][k] bf16 ----------------
__global__ __launch_bounds__(256) void transpose_cvt(const float* __restrict__ W,
                                                     uint16_t* __restrict__ Wt) {
  __shared__ uint16_t tile[32][33];
  const int bx = blockIdx.x * 32;  // n
  const int by = blockIdx.y * 32;  // k
  const int tx = threadIdx.x;      // 0..31
  const int ty = threadIdx.y;      // 0..7
#pragma unroll
  for (int j = 0; j < 4; j++)
    tile[ty + j * 8][tx] = f2bf(W[(size_t)(by + ty + j * 8) * 1024 + bx + tx]);
  __syncthreads();
#pragma unroll
  for (int j = 0; j < 4; j++)
    Wt[(size_t)(bx + ty + j * 8) * 1024 + by + tx] = tile[tx][ty + j * 8];
}

// ---------------- GEMM: C[M][c] = A[M][K=1024] * Wt[c][K=1024]^T ----------------
// MODE 0: QKV projection, N=3072, scatter to Q [BH][S][64], K [BH][S][64], Vt [BH][64][S] (bf16)
// MODE 1: out projection, N=1024, write fp32 C row-major
template <int MODE>
__global__ __launch_bounds__(256) void gemm_bt(const uint16_t* __restrict__ A,
                                               const uint16_t* __restrict__ Bt,
                                               uint16_t* __restrict__ O0,
                                               uint16_t* __restrict__ O1,
                                               uint16_t* __restrict__ O2,
                                               float* __restrict__ OF) {
  __shared__ uint16_t lds[2][128 * 32];  // [0]=A tile [128][32], [1]=B tile [128][32]
  const int tid = threadIdx.x;
  const int lane = tid & 63;
  const int wave = tid >> 6;
  const int wr = wave >> 1, wc = wave & 1;
  const int l15 = lane & 15, lg = lane >> 4;
  const int row0 = blockIdx.y * 128;
  const int col0 = blockIdx.x * 128;

  f32x4 acc[4][4];
#pragma unroll
  for (int i = 0; i < 4; i++)
#pragma unroll
    for (int j = 0; j < 4; j++) acc[i][j] = f32x4{0.f, 0.f, 0.f, 0.f};

  const int srow = tid >> 2;          // 0..63
  const int scb = (tid & 3) * 16;     // byte offset within 64B row
  const char* Ab = (const char*)A;
  const char* Bb = (const char*)Bt;
  char* ldsA = (char*)&lds[0][0];
  char* ldsB = (char*)&lds[1][0];
  const int wbase = wave * 1024;      // wave-uniform LDS offset (HW adds lane*16)

  for (int kt = 0; kt < 1024; kt += 32) {
#pragma unroll
    for (int j = 0; j < 2; ++j) {
      const int r = j * 64 + srow;
      gload_lds16(Ab + ((size_t)(row0 + r) * 1024 + kt) * 2 + scb, ldsA + j * 4096 + wbase);
      gload_lds16(Bb + ((size_t)(col0 + r) * 1024 + kt) * 2 + scb, ldsB + j * 4096 + wbase);
    }
    __syncthreads();
    bf16x8 bfr[4];
#pragma unroll
    for (int ni = 0; ni < 4; ni++)
      bfr[ni] = *(const bf16x8*)&lds[1][(wc * 64 + ni * 16 + l15) * 32 + lg * 8];
#pragma unroll
    for (int mi = 0; mi < 4; mi++) {
      const bf16x8 afr = *(const bf16x8*)&lds[0][(wr * 64 + mi * 16 + l15) * 32 + lg * 8];
#pragma unroll
      for (int ni = 0; ni < 4; ni++) acc[mi][ni] = MFMA16(afr, bfr[ni], acc[mi][ni]);
    }
    __syncthreads();
  }

  // Epilogue. C/D layout: col = lane&15, row = (lane>>4)*4 + i  [m89-verified]
#pragma unroll
  for (int mi = 0; mi < 4; mi++) {
#pragma unroll
    for (int ni = 0; ni < 4; ni++) {
      const int c = col0 + wc * 64 + ni * 16 + l15;
      const int rbase = row0 + wr * 64 + mi * 16 + lg * 4;
#pragma unroll
      for (int i = 0; i < 4; i++) {
        const int r = rbase + i;
        const float v = acc[mi][ni][i];
        if (MODE == 0) {
          const int which = c >> 10, cc = c & 1023;
          const int h = cc >> 6, dh = cc & 63;
          const int b = r >> 11, s = r & 2047;
          const size_t hb = (size_t)(b * NH + h);
          if (which == 0)
            O0[(hb * NS + s) * 64 + dh] = f2bf(v * 0.18033688011112042f);  // (1/8)*log2(e)
          else if (which == 1)
            O1[(hb * NS + s) * 64 + dh] = f2bf(v);
          else
            O2[(hb * 64 + dh) * NS + s] = f2bf(v);
        } else {
          OF[(size_t)r * 1024 + c] = v;
        }
      }
    }
  }
}

// ---------------- causal flash attention ----------------
// grid: (S/64, B*H); 4 waves/block, each wave owns 16 q-rows; KV tiles of 64.
__global__ __launch_bounds__(256) void attn_fwd(const uint16_t* __restrict__ Q,
                                                const uint16_t* __restrict__ K,
                                                const uint16_t* __restrict__ Vt,
                                                uint16_t* __restrict__ Aout) {
  const int qt = blockIdx.x;
  const int bh = blockIdx.y;
  const int lane = threadIdx.x & 63;
  const int w = threadIdx.x >> 6;
  const int l15 = lane & 15, lg = lane >> 4;
  const uint16_t* Qh = Q + (size_t)bh * (NS * 64);
  const uint16_t* Kh = K + (size_t)bh * (NS * 64);
  const uint16_t* Vh = Vt + (size_t)bh * (64 * NS);
  const int qb = qt * 64 + w * 16;

  __shared__ __align__(16) uint16_t plds[4][16][72];  // per-wave P buffer, padded

  const bf16x8 qf0 = *(const bf16x8*)&Qh[(size_t)(qb + l15) * 64 + lg * 8];
  const bf16x8 qf1 = *(const bf16x8*)&Qh[(size_t)(qb + l15) * 64 + 32 + lg * 8];

  f32x4 o[4];
  float mrun[4], lrun[4];
#pragma unroll
  for (int i = 0; i < 4; i++) {
    o[i] = f32x4{0.f, 0.f, 0.f, 0.f};
    mrun[i] = -1e30f;
    lrun[i] = 0.f;
  }

  for (int t = 0; t <= qt; ++t) {
    const int nfmax = (t == qt) ? w : 3;
    f32x4 s[4];
#pragma unroll
    for (int nf = 0; nf < 4; ++nf) {
      if (nf <= nfmax) {
        const uint16_t* kp = &Kh[(size_t)(t * 64 + nf * 16 + l15) * 64 + lg * 8];
        f32x4 a = f32x4{0.f, 0.f, 0.f, 0.f};
        a = MFMA16(qf0, *(const bf16x8*)kp, a);
        a = MFMA16(qf1, *(const bf16x8*)(kp + 32), a);
        if (t == qt && nf == nfmax) {  // diagonal 16x16 fragment: mask col > row
#pragma unroll
          for (int i = 0; i < 4; i++)
            if (l15 > lg * 4 + i) a[i] = -1e30f;
        }
        s[nf] = a;
      } else {
        s[nf] = f32x4{-1e30f, -1e30f, -1e30f, -1e30f};
      }
    }
    // online softmax (rows live in 16-lane groups; i indexes this lane's 4 rows)
    float rmax[4];
#pragma unroll
    for (int i = 0; i < 4; i++)
      rmax[i] = fmaxf(fmaxf(s[0][i], s[1][i]), fmaxf(s[2][i], s[3][i]));
#pragma unroll
    for (int m = 1; m < 16; m <<= 1)
#pragma unroll
      for (int i = 0; i < 4; i++) rmax[i] = fmaxf(rmax[i], __shfl_xor(rmax[i], m));
    float alpha[4];
#pragma unroll
    for (int i = 0; i < 4; i++) {
      const float mn = fmaxf(mrun[i], rmax[i]);
      alpha[i] = exp2f(mrun[i] - mn);
      mrun[i] = mn;
    }
    float rsum[4] = {0.f, 0.f, 0.f, 0.f};
#pragma unroll
    for (int nf = 0; nf < 4; ++nf)
#pragma unroll
      for (int i = 0; i < 4; i++) {
        const float p = exp2f(s[nf][i] - mrun[i]);
        s[nf][i] = p;
        rsum[i] += p;
      }
#pragma unroll
    for (int m = 1; m < 16; m <<= 1)
#pragma unroll
      for (int i = 0; i < 4; i++) rsum[i] += __shfl_xor(rsum[i], m);
#pragma unroll
    for (int i = 0; i < 4; i++) lrun[i] = lrun[i] * alpha[i] + rsum[i];
#pragma unroll
    for (int df = 0; df < 4; ++df) {
      f32x4 t4 = o[df];
#pragma unroll
      for (int i = 0; i < 4; i++) t4[i] *= alpha[i];
      o[df] = t4;
    }
    // P -> LDS (C-layout -> A-layout re-distribution)
#pragma unroll
    for (int nf = 0; nf < 4; ++nf)
#pragma unroll
      for (int i = 0; i < 4; i++) plds[w][lg * 4 + i][nf * 16 + l15] = f2bf(s[nf][i]);
    __syncthreads();
    const bf16x8 pa0 = *(const bf16x8*)&plds[w][l15][lg * 8];
    const bf16x8 pa1 = *(const bf16x8*)&plds[w][l15][32 + lg * 8];
#pragma unroll
    for (int df = 0; df < 4; ++df) {
      const uint16_t* vp = &Vh[(size_t)(df * 16 + l15) * NS + t * 64 + lg * 8];
      o[df] = MFMA16(pa0, *(const bf16x8*)vp, o[df]);
      o[df] = MFMA16(pa1, *(const bf16x8*)(vp + 32), o[df]);
    }
    __syncthreads();
  }

  const int b = bh >> 4, h = bh & 15;
#pragma unroll
  for (int df = 0; df < 4; ++df) {
#pragma unroll
    for (int i = 0; i < 4; i++) {
      const int q = qb + lg * 4 + i;
      const float v = o[df][i] / lrun[i];
      Aout[((size_t)(b * NS + q)) * 1024 + h * 64 + df * 16 + l15] = f2bf(v);
    }
  }
}

extern "C" void kernel_launch(void* const* d_in, const int* in_sizes, int n_in,
                              void* d_out, int out_size, void* d_ws, size_t ws_size,
                              hipStream_t stream) {
  const float* x = (const float*)d_in[0];
  const float* Wq = (const float*)d_in[1];
  const float* Wk = (const float*)d_in[2];
  const float* Wv = (const float*)d_in[3];
  const float* Wo = (const float*)d_in[4];
  float* out = (float*)d_out;

  char* ws = (char*)d_ws;
  uint16_t* xb = (uint16_t*)(ws);                        // 16 MB  (reused as attn buffer)
  uint16_t* Wt3 = (uint16_t*)(ws + (16u << 20));         // 6 MB   [3][1024][1024] (n-major)
  uint16_t* Wot = (uint16_t*)(ws + (22u << 20));         // 2 MB
  uint16_t* Qb = (uint16_t*)(ws + (24u << 20));          // 16 MB  [BH][S][64]
  uint16_t* Kb = (uint16_t*)(ws + (40u << 20));          // 16 MB  [BH][S][64]
  uint16_t* Vt = (uint16_t*)(ws + (56u << 20));          // 16 MB  [BH][64][S]
  uint16_t* attn = xb;                                   // total 72 MB

  cvt_bf16_kernel<<<8192, 256, 0, stream>>>(x, xb, (NB * NS * ND) / 4);
  dim3 tb(32, 8);
  transpose_cvt<<<dim3(32, 32), tb, 0, stream>>>(Wq, Wt3);
  transpose_cvt<<<dim3(32, 32), tb, 0, stream>>>(Wk, Wt3 + (1u << 20));
  transpose_cvt<<<dim3(32, 32), tb, 0, stream>>>(Wv, Wt3 + (2u << 20));
  transpose_cvt<<<dim3(32, 32), tb, 0, stream>>>(Wo, Wot);

  gemm_bt<0><<<dim3(24, 64), 256, 0, stream>>>(xb, Wt3, Qb, Kb, Vt, nullptr);
  attn_fwd<<<dim3(NS / 64, NB * NH), 256, 0, stream>>>(Qb, Kb, Vt, attn);
  gemm_bt<1><<<dim3(8, 64), 256, 0, stream>>>(attn, Wot, nullptr, nullptr, nullptr, out);
}

// Round 2
// 374.855 us; speedup vs baseline: 1.6294x; 1.6294x over previous
//
#include <hip/hip_runtime.h>
#include <stdint.h>

// Shapes (fixed): B=4, S=2048, D=1024, H=16, DH=64
#define NB 4
#define NS 2048
#define ND 1024
#define NH 16
#define NDH 64

typedef __attribute__((ext_vector_type(8))) short bf16x8;
typedef __attribute__((ext_vector_type(4))) float f32x4;

#define MFMA16(a, b, c) __builtin_amdgcn_mfma_f32_16x16x32_bf16((a), (b), (c), 0, 0, 0)

__device__ __forceinline__ uint16_t f2bf(float f) {
  uint32_t u = __builtin_bit_cast(uint32_t, f);
  return (uint16_t)((u + 0x7FFFu + ((u >> 16) & 1u)) >> 16);
}

__device__ __forceinline__ void gload_lds16(const void* g, void* l) {
  __builtin_amdgcn_global_load_lds(
      (const __attribute__((address_space(1))) uint32_t*)(uintptr_t)g,
      (__attribute__((address_space(3))) uint32_t*)(uintptr_t)l, 16, 0, 0);
}

// ---------------- fp32 -> bf16 convert (x) ----------------
__global__ __launch_bounds__(256) void cvt_bf16_kernel(const float* __restrict__ src,
                                                       uint16_t* __restrict__ dst, int n4) {
  int i = blockIdx.x * 256 + threadIdx.x;
  if (i >= n4) return;
  const float4 f = *(const float4*)(src + (size_t)i * 4);
  union { uint16_t u[4]; uint64_t q; } o;
  o.u[0] = f2bf(f.x); o.u[1] = f2bf(f.y); o.u[2] = f2bf(f.z); o.u[3] = f2bf(f.w);
  *(uint64_t*)(dst + (size_t)i * 4) = o.q;
}

// ---------------- transpose + convert: W[1024][1024] f32 -> Wt[n][k] bf16 ----------------
__global__ __launch_bounds__(256) void transpose_cvt(const float* __restrict__ W,
                                                     uint16_t* __restrict__ Wt) {
  __shared__ uint16_t tile[32][33];
  const int bx = blockIdx.x * 32;  // n
  const int by = blockIdx.y * 32;  // k
  const int tx = threadIdx.x;      // 0..31
  const int ty = threadIdx.y;      // 0..7
#pragma unroll
  for (int j = 0; j < 4; j++)
    tile[ty + j * 8][tx] = f2bf(W[(size_t)(by + ty + j * 8) * 1024 + bx + tx]);
  __syncthreads();
#pragma unroll
  for (int j = 0; j < 4; j++)
    Wt[(size_t)(bx + ty + j * 8) * 1024 + by + tx] = tile[tx][ty + j * 8];
}

// ---------------- GEMM: C[M][c] = A[M][K=1024] * Wt[c][K=1024]^T ----------------
// MODE 0: QKV projection, N=3072, scatter to Q [BH][S][64], K [BH][S][64], Vt [BH][64][S] (bf16)
// MODE 1: out projection, N=1024, write fp32 C row-major
template <int MODE>
__global__ __launch_bounds__(256) void gemm_bt(const uint16_t* __restrict__ A,
                                               const uint16_t* __restrict__ Bt,
                                               uint16_t* __restrict__ O0,
                                               uint16_t* __restrict__ O1,
                                               uint16_t* __restrict__ O2,
                                               float* __restrict__ OF) {
  __shared__ uint16_t lds[2][128 * 32];  // [0]=A tile [128][32], [1]=B tile [128][32]
  const int tid = threadIdx.x;
  const int lane = tid & 63;
  const int wave = tid >> 6;
  const int wr = wave >> 1, wc = wave & 1;
  const int l15 = lane & 15, lg = lane >> 4;
  const int row0 = blockIdx.y * 128;
  const int col0 = blockIdx.x * 128;

  f32x4 acc[4][4];
#pragma unroll
  for (int i = 0; i < 4; i++)
#pragma unroll
    for (int j = 0; j < 4; j++) acc[i][j] = f32x4{0.f, 0.f, 0.f, 0.f};

  const int srow = tid >> 2;          // 0..63
  const int scb = (tid & 3) * 16;     // byte offset within 64B row
  const char* Ab = (const char*)A;
  const char* Bb = (const char*)Bt;
  char* ldsA = (char*)&lds[0][0];
  char* ldsB = (char*)&lds[1][0];
  const int wbase = wave * 1024;      // wave-uniform LDS offset (HW adds lane*16)

  for (int kt = 0; kt < 1024; kt += 32) {
#pragma unroll
    for (int j = 0; j < 2; ++j) {
      const int r = j * 64 + srow;
      gload_lds16(Ab + ((size_t)(row0 + r) * 1024 + kt) * 2 + scb, ldsA + j * 4096 + wbase);
      gload_lds16(Bb + ((size_t)(col0 + r) * 1024 + kt) * 2 + scb, ldsB + j * 4096 + wbase);
    }
    __syncthreads();
    bf16x8 bfr[4];
#pragma unroll
    for (int ni = 0; ni < 4; ni++)
      bfr[ni] = *(const bf16x8*)&lds[1][(wc * 64 + ni * 16 + l15) * 32 + lg * 8];
#pragma unroll
    for (int mi = 0; mi < 4; mi++) {
      const bf16x8 afr = *(const bf16x8*)&lds[0][(wr * 64 + mi * 16 + l15) * 32 + lg * 8];
#pragma unroll
      for (int ni = 0; ni < 4; ni++) acc[mi][ni] = MFMA16(afr, bfr[ni], acc[mi][ni]);
    }
    __syncthreads();
  }

  // Epilogue. C/D layout: col = lane&15, row = (lane>>4)*4 + i  [m89-verified]
#pragma unroll
  for (int mi = 0; mi < 4; mi++) {
#pragma unroll
    for (int ni = 0; ni < 4; ni++) {
      const int c = col0 + wc * 64 + ni * 16 + l15;
      const int rbase = row0 + wr * 64 + mi * 16 + lg * 4;
#pragma unroll
      for (int i = 0; i < 4; i++) {
        const int r = rbase + i;
        const float v = acc[mi][ni][i];
        if (MODE == 0) {
          const int which = c >> 10, cc = c & 1023;
          const int h = cc >> 6, dh = cc & 63;
          const int b = r >> 11, s = r & 2047;
          const size_t hb = (size_t)(b * NH + h);
          if (which == 0)
            O0[(hb * NS + s) * 64 + dh] = f2bf(v * 0.18033688011112042f);  // (1/8)*log2(e)
          else if (which == 1)
            O1[(hb * NS + s) * 64 + dh] = f2bf(v);
          else
            O2[(hb * 64 + dh) * NS + s] = f2bf(v);
        } else {
          OF[(size_t)r * 1024 + c] = v;
        }
      }
    }
  }
}

// ---------------- causal flash attention (1 wave / block, paired q-groups) ----------------
// flat grid 4096: xcd-aware decode -> (bh, pair p). Wave handles q-groups p and 127-p
// (16 rows each) sequentially -> constant ~33 KV-tile iterations per block.
__global__ __launch_bounds__(64) void attn_fwd(const uint16_t* __restrict__ Q,
                                               const uint16_t* __restrict__ K,
                                               const uint16_t* __restrict__ Vt,
                                               uint16_t* __restrict__ Aout) {
  const int wgid = blockIdx.x;
  const int xcd = wgid & 7;
  const int slot = wgid >> 3;
  const int bh = ((slot & 7) << 3) | xcd;  // all blocks of head bh land on one XCD
  const int p = slot >> 3;                 // pair index 0..63

  const int lane = threadIdx.x;
  const int l15 = lane & 15, lg = lane >> 4;
  const uint16_t* Qh = Q + (size_t)bh * (NS * 64);
  const uint16_t* Kh = K + (size_t)bh * (NS * 64);
  const uint16_t* Vh = Vt + (size_t)bh * (64 * NS);
  const int b = bh >> 4, h = bh & 15;

  // per-wave P buffer; row stride 68 u16 = 136 B = 34 banks (34%8==2 -> the four
  // lg row-groups (rows 4 apart) land on disjoint 8-bank sets: conflict-free writes)
  __shared__ __align__(16) uint16_t plds[16][68];

  for (int seg = 0; seg < 2; ++seg) {
    const int g = seg ? (127 - p) : p;  // q-group: rows [16g, 16g+16)
    const int qb = g * 16;
    const int tmax = g >> 2;   // last KV tile index
    const int nfd = g & 3;     // diagonal fragment within last tile

    const bf16x8 qf0 = *(const bf16x8*)&Qh[(size_t)(qb + l15) * 64 + lg * 8];
    const bf16x8 qf1 = *(const bf16x8*)&Qh[(size_t)(qb + l15) * 64 + 32 + lg * 8];

    f32x4 o[4];
    float mrun[4], lrun[4];
#pragma unroll
    for (int i = 0; i < 4; i++) {
      o[i] = f32x4{0.f, 0.f, 0.f, 0.f};
      mrun[i] = -1e30f;
      lrun[i] = 0.f;
    }

    for (int t = 0; t <= tmax; ++t) {
      const int nfmax = (t == tmax) ? nfd : 3;
      f32x4 s[4];
#pragma unroll
      for (int nf = 0; nf < 4; ++nf) {
        if (nf <= nfmax) {
          const uint16_t* kp = &Kh[(size_t)(t * 64 + nf * 16 + l15) * 64 + lg * 8];
          f32x4 a = f32x4{0.f, 0.f, 0.f, 0.f};
          a = MFMA16(qf0, *(const bf16x8*)kp, a);
          a = MFMA16(qf1, *(const bf16x8*)(kp + 32), a);
          if (t == tmax && nf == nfd) {  // diagonal 16x16 fragment: mask col > row
#pragma unroll
            for (int i = 0; i < 4; i++)
              if (l15 > lg * 4 + i) a[i] = -1e30f;
          }
          s[nf] = a;
        } else {
          s[nf] = f32x4{-1e30f, -1e30f, -1e30f, -1e30f};
        }
      }
      // online softmax (row r = lg*4+i lives across the 16 l15-lanes)
      float rmax[4];
#pragma unroll
      for (int i = 0; i < 4; i++)
        rmax[i] = fmaxf(fmaxf(s[0][i], s[1][i]), fmaxf(s[2][i], s[3][i]));
#pragma unroll
      for (int m = 1; m < 16; m <<= 1)
#pragma unroll
        for (int i = 0; i < 4; i++) rmax[i] = fmaxf(rmax[i], __shfl_xor(rmax[i], m));
      float alpha[4];
#pragma unroll
      for (int i = 0; i < 4; i++) {
        const float mn = fmaxf(mrun[i], rmax[i]);
        alpha[i] = exp2f(mrun[i] - mn);
        mrun[i] = mn;
      }
      float rsum[4] = {0.f, 0.f, 0.f, 0.f};
#pragma unroll
      for (int nf = 0; nf < 4; ++nf)
#pragma unroll
        for (int i = 0; i < 4; i++) {
          const float pr = exp2f(s[nf][i] - mrun[i]);
          s[nf][i] = pr;
          rsum[i] += pr;
        }
#pragma unroll
      for (int m = 1; m < 16; m <<= 1)
#pragma unroll
        for (int i = 0; i < 4; i++) rsum[i] += __shfl_xor(rsum[i], m);
#pragma unroll
      for (int i = 0; i < 4; i++) lrun[i] = lrun[i] * alpha[i] + rsum[i];
#pragma unroll
      for (int df = 0; df < 4; ++df) {
        f32x4 t4 = o[df];
#pragma unroll
        for (int i = 0; i < 4; i++) t4[i] *= alpha[i];
        o[df] = t4;
      }
      // P -> LDS (C-layout -> A-layout re-distribution); wave-private, no barrier
#pragma unroll
      for (int nf = 0; nf < 4; ++nf)
#pragma unroll
        for (int i = 0; i < 4; i++) plds[lg * 4 + i][nf * 16 + l15] = f2bf(s[nf][i]);
      const bf16x8 pa0 = *(const bf16x8*)&plds[l15][lg * 8];
      const bf16x8 pa1 = *(const bf16x8*)&plds[l15][32 + lg * 8];
#pragma unroll
      for (int df = 0; df < 4; ++df) {
        const uint16_t* vp = &Vh[(size_t)(df * 16 + l15) * NS + t * 64 + lg * 8];
        o[df] = MFMA16(pa0, *(const bf16x8*)vp, o[df]);
        o[df] = MFMA16(pa1, *(const bf16x8*)(vp + 32), o[df]);
      }
    }

#pragma unroll
    for (int df = 0; df < 4; ++df) {
#pragma unroll
      for (int i = 0; i < 4; i++) {
        const int q = qb + lg * 4 + i;
        const float v = o[df][i] / lrun[i];
        Aout[((size_t)(b * NS + q)) * 1024 + h * 64 + df * 16 + l15] = f2bf(v);
      }
    }
  }
}

extern "C" void kernel_launch(void* const* d_in, const int* in_sizes, int n_in,
                              void* d_out, int out_size, void* d_ws, size_t ws_size,
                              hipStream_t stream) {
  const float* x = (const float*)d_in[0];
  const float* Wq = (const float*)d_in[1];
  const float* Wk = (const float*)d_in[2];
  const float* Wv = (const float*)d_in[3];
  const float* Wo = (const float*)d_in[4];
  float* out = (float*)d_out;

  char* ws = (char*)d_ws;
  uint16_t* xb = (uint16_t*)(ws);                        // 16 MB  (reused as attn buffer)
  uint16_t* Wt3 = (uint16_t*)(ws + (16u << 20));         // 6 MB   [3][1024][1024] (n-major)
  uint16_t* Wot = (uint16_t*)(ws + (22u << 20));         // 2 MB
  uint16_t* Qb = (uint16_t*)(ws + (24u << 20));          // 16 MB  [BH][S][64]
  uint16_t* Kb = (uint16_t*)(ws + (40u << 20));          // 16 MB  [BH][S][64]
  uint16_t* Vt = (uint16_t*)(ws + (56u << 20));          // 16 MB  [BH][64][S]
  uint16_t* attn = xb;                                   // total 72 MB

  cvt_bf16_kernel<<<8192, 256, 0, stream>>>(x, xb, (NB * NS * ND) / 4);
  dim3 tb(32, 8);
  transpose_cvt<<<dim3(32, 32), tb, 0, stream>>>(Wq, Wt3);
  transpose_cvt<<<dim3(32, 32), tb, 0, stream>>>(Wk, Wt3 + (1u << 20));
  transpose_cvt<<<dim3(32, 32), tb, 0, stream>>>(Wv, Wt3 + (2u << 20));
  transpose_cvt<<<dim3(32, 32), tb, 0, stream>>>(Wo, Wot);

  gemm_bt<0><<<dim3(24, 64), 256, 0, stream>>>(xb, Wt3, Qb, Kb, Vt, nullptr);
  attn_fwd<<<4096, 64, 0, stream>>>(Qb, Kb, Vt, attn);
  gemm_bt<1><<<dim3(8, 64), 256, 0, stream>>>(attn, Wot, nullptr, nullptr, nullptr, out);
}